// Round 1
// baseline (1146.243 us; speedup 1.0000x reference)
//
#include <hip/hip_runtime.h>
#include <hip/hip_bf16.h>

#define N_NODES  100000
#define N_GRAPHS 512
#define IN_CH    128
#define HID      32
#define OUT_CH   10
#define N_EDGES  3200000
#define NCHUNK   98   // ceil(100000 / 1024)

// ---- int32/int64 index loader (low word of little-endian int64) ----
__device__ __forceinline__ int load_idx(const int* __restrict__ p, long long pos, int is64) {
  return is64 ? p[2 * pos] : p[(int)pos];
}

// Detect whether edge_index buffer is int64: sample first 4096 "odd words";
// if data is int64, they are all high-words of values < 2^31 => all zero.
// If int32, they are random node ids in [0,100000) => ~surely nonzero.
__global__ void detect_i64(const int* __restrict__ ei, int* __restrict__ flag) {
  __shared__ int any_nz;
  if (threadIdx.x == 0) any_nz = 0;
  __syncthreads();
  for (int i = threadIdx.x; i < 4096; i += 256) {
    if (ei[2 * i + 1] != 0) any_nz = 1;
  }
  __syncthreads();
  if (threadIdx.x == 0) flag[0] = any_nz ? 0 : 1;
}

// ---- degree histogram over dst ----
__global__ void hist_k(const int* __restrict__ ei, const int* __restrict__ flag,
                       int* __restrict__ deg) {
  int e = blockIdx.x * 256 + threadIdx.x;
  if (e >= N_EDGES) return;
  int is64 = flag[0];
  int d = load_idx(ei, (long long)N_EDGES + e, is64);
  atomicAdd(&deg[d], 1);
}

__global__ void dinv_k(const int* __restrict__ deg, float* __restrict__ dinv) {
  int n = blockIdx.x * 256 + threadIdx.x;
  if (n < N_NODES) dinv[n] = rsqrtf((float)(deg[n] + 1));  // +1 self-loop
}

// ---- two-level exclusive scan of deg -> row_ptr (and cursor copy) ----
__global__ void scan_p1(const int* __restrict__ deg, int* __restrict__ bsum) {
  __shared__ int sdata[256];
  int b = blockIdx.x, t = threadIdx.x;
  int base = b * 1024;
  int s = 0;
  for (int i = 0; i < 4; i++) {
    int idx = base + t + i * 256;
    if (idx < N_NODES) s += deg[idx];
  }
  sdata[t] = s;
  __syncthreads();
  for (int off = 128; off > 0; off >>= 1) {
    if (t < off) sdata[t] += sdata[t + off];
    __syncthreads();
  }
  if (t == 0) bsum[b] = sdata[0];
}

__global__ void scan_p2(int* __restrict__ bsum, int n) {
  __shared__ int sd[128];
  int t = threadIdx.x;
  int orig = (t < n) ? bsum[t] : 0;
  sd[t] = orig;
  __syncthreads();
  for (int off = 1; off < 128; off <<= 1) {
    int u = (t >= off) ? sd[t - off] : 0;
    __syncthreads();
    sd[t] += u;
    __syncthreads();
  }
  if (t < n) bsum[t] = sd[t] - orig;  // exclusive
}

__global__ void scan_p3(const int* __restrict__ deg, const int* __restrict__ bsum,
                        int* __restrict__ row_ptr, int* __restrict__ cursor) {
  __shared__ int sdata[256];
  int b = blockIdx.x, t = threadIdx.x;
  int base = b * 1024;
  int v[4];
  int s = 0;
  for (int i = 0; i < 4; i++) {
    int idx = base + t * 4 + i;
    v[i] = (idx < N_NODES) ? deg[idx] : 0;
    s += v[i];
  }
  sdata[t] = s;
  __syncthreads();
  int own = s;
  for (int off = 1; off < 256; off <<= 1) {
    int u = (t >= off) ? sdata[t - off] : 0;
    __syncthreads();
    sdata[t] += u;
    __syncthreads();
  }
  int excl = sdata[t] - own + bsum[b];
  for (int i = 0; i < 4; i++) {
    int idx = base + t * 4 + i;
    if (idx < N_NODES) {
      row_ptr[idx] = excl;
      cursor[idx]  = excl;
      excl += v[i];
    }
  }
}

// ---- scatter edges into CSR (by dst, storing src) ----
__global__ void scatter_k(const int* __restrict__ ei, const int* __restrict__ flag,
                          int* __restrict__ cursor, int* __restrict__ csr) {
  int e = blockIdx.x * 256 + threadIdx.x;
  if (e >= N_EDGES) return;
  int is64 = flag[0];
  int s = load_idx(ei, (long long)e, is64);
  int d = load_idx(ei, (long long)N_EDGES + e, is64);
  int pos = atomicAdd(&cursor[d], 1);
  csr[pos] = s;
}

// ---- G = (X @ W) * dinv[row] ;  X:[n,K], W:[K,32] ----
template <int K>
__global__ void gemm_scale(const float* __restrict__ X, const float* __restrict__ W,
                           const float* __restrict__ dinv, float* __restrict__ G,
                           int nrows) {
  __shared__ float Ws[K * HID];
  __shared__ float Xs[8 * K];
  for (int i = threadIdx.x; i < K * HID; i += 256) Ws[i] = W[i];
  int c = threadIdx.x & 31, r = threadIdx.x >> 5;
  int ntiles = nrows / 8;
  for (int tile = blockIdx.x; tile < ntiles; tile += gridDim.x) {
    int row0 = tile * 8;
    __syncthreads();
    for (int i = threadIdx.x; i < 8 * K; i += 256) Xs[i] = X[row0 * K + i];
    __syncthreads();
    int row = row0 + r;
    float acc = 0.f;
#pragma unroll
    for (int k = 0; k < K; k++) acc += Xs[r * K + k] * Ws[k * 32 + c];
    G[row * 32 + c] = acc * dinv[row];
  }
}

// ---- out[d] = act( dinv[d] * (sum_{src in N(d)} g[src] + g[d]) + b ) ----
__global__ void agg_k(const float* __restrict__ g, const int* __restrict__ csr,
                      const int* __restrict__ row_ptr, const int* __restrict__ deg,
                      const float* __restrict__ dinv, const float* __restrict__ bias,
                      float* __restrict__ out, int do_relu) {
  int node = blockIdx.x * 4 + (threadIdx.x >> 6);
  if (node >= N_NODES) return;
  int lane = threadIdx.x & 63;
  int feat = lane & 31;
  int half = lane >> 5;
  int start = row_ptr[node];
  int dn = deg[node];
  float acc = 0.f;
  for (int i = half; i < dn; i += 2) {
    int s = csr[start + i];
    acc += g[s * HID + feat];
  }
  acc += __shfl_xor(acc, 32, 64);   // combine the two half-wave partials
  acc += g[node * HID + feat];      // self-loop
  float r = dinv[node] * acc + bias[feat];
  if (do_relu) r = fmaxf(r, 0.f);
  if (half == 0) out[node * HID + feat] = r;
}

// ---- mean-pool accumulate ----
__global__ void pool_k(const float* __restrict__ h, const int* __restrict__ batch,
                       const int* __restrict__ flag, float* __restrict__ pool,
                       float* __restrict__ cnt) {
  int idx = blockIdx.x * 256 + threadIdx.x;
  if (idx >= N_NODES * HID) return;
  int n = idx >> 5, c = idx & 31;
  int is64 = flag[0];
  int b = load_idx(batch, (long long)n, is64);
  atomicAdd(&pool[b * HID + c], h[idx]);
  if (c == 0) atomicAdd(&cnt[b], 1.0f);
}

// ---- head: out = (pool/cnt) @ Wl + bl ----
__global__ void final_k(const float* __restrict__ pool, const float* __restrict__ cnt,
                        const float* __restrict__ Wl, const float* __restrict__ bl,
                        float* __restrict__ out) {
  int i = blockIdx.x * 256 + threadIdx.x;
  if (i >= N_GRAPHS * OUT_CH) return;
  int gi = i / OUT_CH, o = i % OUT_CH;
  float c = fmaxf(cnt[gi], 1.0f);
  float acc = bl[o];
#pragma unroll
  for (int k = 0; k < HID; k++) acc += (pool[gi * HID + k] / c) * Wl[k * OUT_CH + o];
  out[i] = acc;
}

extern "C" void kernel_launch(void* const* d_in, const int* in_sizes, int n_in,
                              void* d_out, int out_size, void* d_ws, size_t ws_size,
                              hipStream_t stream) {
  const float* x   = (const float*)d_in[0];
  const int* ei    = (const int*)d_in[1];
  const int* batch = (const int*)d_in[2];
  const float* W1  = (const float*)d_in[3];
  const float* b1  = (const float*)d_in[4];
  const float* W2  = (const float*)d_in[5];
  const float* b2  = (const float*)d_in[6];
  const float* W3  = (const float*)d_in[7];
  const float* b3  = (const float*)d_in[8];
  const float* Wl  = (const float*)d_in[9];
  const float* bl  = (const float*)d_in[10];
  float* out = (float*)d_out;

  char* p = (char*)d_ws;
  auto alloc = [&](size_t bytes) {
    void* r = (void*)p;
    p += (bytes + 255) & ~(size_t)255;
    return r;
  };
  int*   deg     = (int*)alloc((size_t)N_NODES * 4);
  int*   row_ptr = (int*)alloc((size_t)N_NODES * 4);
  int*   cursor  = (int*)alloc((size_t)N_NODES * 4);
  float* dinv    = (float*)alloc((size_t)N_NODES * 4);
  int*   bsum    = (int*)alloc((size_t)NCHUNK * 4);
  int*   flag    = (int*)alloc(4);
  int*   csr     = (int*)alloc((size_t)N_EDGES * 4);
  float* g       = (float*)alloc((size_t)N_NODES * HID * 4);
  float* h       = (float*)alloc((size_t)N_NODES * HID * 4);
  float* pool    = (float*)alloc((size_t)N_GRAPHS * HID * 4);
  float* cnt     = (float*)alloc((size_t)N_GRAPHS * 4);

  hipMemsetAsync(deg, 0, (size_t)N_NODES * 4, stream);
  hipMemsetAsync(pool, 0, (size_t)N_GRAPHS * HID * 4, stream);
  hipMemsetAsync(cnt, 0, (size_t)N_GRAPHS * 4, stream);

  detect_i64<<<1, 256, 0, stream>>>(ei, flag);
  hist_k<<<(N_EDGES + 255) / 256, 256, 0, stream>>>(ei, flag, deg);
  dinv_k<<<(N_NODES + 255) / 256, 256, 0, stream>>>(deg, dinv);
  scan_p1<<<NCHUNK, 256, 0, stream>>>(deg, bsum);
  scan_p2<<<1, 128, 0, stream>>>(bsum, NCHUNK);
  scan_p3<<<NCHUNK, 256, 0, stream>>>(deg, bsum, row_ptr, cursor);
  scatter_k<<<(N_EDGES + 255) / 256, 256, 0, stream>>>(ei, flag, cursor, csr);

  gemm_scale<IN_CH><<<2048, 256, 0, stream>>>(x, W1, dinv, g, N_NODES);
  agg_k<<<N_NODES / 4, 256, 0, stream>>>(g, csr, row_ptr, deg, dinv, b1, h, 1);
  gemm_scale<HID><<<2048, 256, 0, stream>>>(h, W2, dinv, g, N_NODES);
  agg_k<<<N_NODES / 4, 256, 0, stream>>>(g, csr, row_ptr, deg, dinv, b2, h, 1);
  gemm_scale<HID><<<2048, 256, 0, stream>>>(h, W3, dinv, g, N_NODES);
  agg_k<<<N_NODES / 4, 256, 0, stream>>>(g, csr, row_ptr, deg, dinv, b3, h, 0);

  pool_k<<<(N_NODES * HID + 255) / 256, 256, 0, stream>>>(h, batch, flag, pool, cnt);
  final_k<<<(N_GRAPHS * OUT_CH + 255) / 256, 256, 0, stream>>>(pool, cnt, Wl, bl, out);
}